// Round 1
// baseline (1696.516 us; speedup 1.0000x reference)
//
#include <hip/hip_runtime.h>
#include <hip/hip_bf16.h>

// Instant-NGP style fused hash-grid encode + 3-layer MLP, fp32 throughout.
// One thread per point. Weights staged in LDS (broadcast reads); activations
// round-trip through a per-thread-column LDS stage so GEMM k-loops stay
// runtime (small I-footprint) while accumulators stay in registers.

#define NLVL 16
#define TSZ   524288u          // hash table entries per level (2^19)
#define TMASK 524287u
#define PR1 2654435761u
#define PR2 805459861u

// floor(16 * 1.5^l), exact in fp64
__device__ __constant__ int kResC[NLVL] = {16,24,36,54,81,121,182,273,410,615,922,1383,2075,3113,4670,7006};
constexpr int kRes[NLVL] = {16,24,36,54,81,121,182,273,410,615,922,1383,2075,3113,4670,7006};
// dense iff (res+1)^3 <= T: true for res 16,24,36,54 (82^3 > 2^19)
constexpr bool kDense[NLVL] = {true,true,true,true,false,false,false,false,
                               false,false,false,false,false,false,false,false};

__global__ __launch_bounds__(256)
void ngp_fused_kernel(const float* __restrict__ x,
                      const float* __restrict__ table,
                      const float* __restrict__ W1,
                      const float* __restrict__ W2,
                      const float* __restrict__ W3,
                      float* __restrict__ out,
                      int n)
{
    __shared__ float sW1[32 * 64];   //  8 KB
    __shared__ float sW2[64 * 64];   // 16 KB
    __shared__ float sW3[64 * 16];   //  4 KB
    __shared__ float hS[32 * 256];   // 32 KB activation stage: [k][tid], conflict-free

    const int t = threadIdx.x;

    // ---- stage weights (coalesced, once per block) ----
#pragma unroll
    for (int r = 0; r < 8; ++r)  sW1[r * 256 + t] = W1[r * 256 + t];
#pragma unroll
    for (int r = 0; r < 16; ++r) sW2[r * 256 + t] = W2[r * 256 + t];
#pragma unroll
    for (int r = 0; r < 4; ++r)  sW3[r * 256 + t] = W3[r * 256 + t];
    __syncthreads();

    const int i = blockIdx.x * 256 + t;
    if (i >= n) return;   // no barriers below (hS is per-thread-column only)

    const float px = x[3 * i + 0];
    const float py = x[3 * i + 1];
    const float pz = x[3 * i + 2];

    // ================= hash-grid encode: h[32] =================
    float h[32];
#pragma unroll
    for (int l = 0; l < NLVL; ++l) {
        const float res = (float)kRes[l];
        const float fx = px * res, fy = py * res, fz = pz * res;
        const float bx = floorf(fx), by = floorf(fy), bz = floorf(fz);
        const float wx = fx - bx, wy = fy - by, wz = fz - bz;
        const unsigned cx = (unsigned)bx, cy = (unsigned)by, cz = (unsigned)bz;

        unsigned i0, i1, i2, i3, i4, i5, i6, i7;
        if (kDense[l]) {
            const unsigned s  = (unsigned)kRes[l] + 1u;
            const unsigned s2 = s * s;
            const unsigned b  = cx + cy * s + cz * s2;
            // corner c = (i,j,k): bit2->x, bit1->y, bit0->z (OFFSETS order)
            i0 = b;            i1 = b + s2;
            i2 = b + s;        i3 = b + s + s2;
            i4 = b + 1u;       i5 = b + 1u + s2;
            i6 = b + 1u + s;   i7 = b + 1u + s + s2;
        } else {
            const unsigned hx0 = cx,        hx1 = cx + 1u;
            const unsigned hy0 = cy * PR1,  hy1 = hy0 + PR1;
            const unsigned hz0 = cz * PR2,  hz1 = hz0 + PR2;
            i0 = (hx0 ^ hy0 ^ hz0) & TMASK;  i1 = (hx0 ^ hy0 ^ hz1) & TMASK;
            i2 = (hx0 ^ hy1 ^ hz0) & TMASK;  i3 = (hx0 ^ hy1 ^ hz1) & TMASK;
            i4 = (hx1 ^ hy0 ^ hz0) & TMASK;  i5 = (hx1 ^ hy0 ^ hz1) & TMASK;
            i6 = (hx1 ^ hy1 ^ hz0) & TMASK;  i7 = (hx1 ^ hy1 ^ hz1) & TMASK;
        }

        const float2* __restrict__ tl =
            reinterpret_cast<const float2*>(table) + (size_t)l * TSZ;
        const float2 f0 = tl[i0], f1 = tl[i1], f2 = tl[i2], f3 = tl[i3];
        const float2 f4 = tl[i4], f5 = tl[i5], f6 = tl[i6], f7 = tl[i7];

        const float ax = 1.f - wx, ay = 1.f - wy, az = 1.f - wz;
        const float g00 = ax * ay, g01 = ax * wy, g10 = wx * ay, g11 = wx * wy;
        float a0 = 0.f, a1 = 0.f, v;
        v = g00 * az; a0 = fmaf(v, f0.x, a0); a1 = fmaf(v, f0.y, a1);
        v = g00 * wz; a0 = fmaf(v, f1.x, a0); a1 = fmaf(v, f1.y, a1);
        v = g01 * az; a0 = fmaf(v, f2.x, a0); a1 = fmaf(v, f2.y, a1);
        v = g01 * wz; a0 = fmaf(v, f3.x, a0); a1 = fmaf(v, f3.y, a1);
        v = g10 * az; a0 = fmaf(v, f4.x, a0); a1 = fmaf(v, f4.y, a1);
        v = g10 * wz; a0 = fmaf(v, f5.x, a0); a1 = fmaf(v, f5.y, a1);
        v = g11 * az; a0 = fmaf(v, f6.x, a0); a1 = fmaf(v, f6.y, a1);
        v = g11 * wz; a0 = fmaf(v, f7.x, a0); a1 = fmaf(v, f7.y, a1);
        h[2 * l + 0] = a0;
        h[2 * l + 1] = a1;
    }

    // ================= layer 1: h[32] @ W1[32,64], relu =================
#pragma unroll
    for (int k = 0; k < 32; ++k) hS[k * 256 + t] = h[k];

    float h1[64];
#pragma unroll
    for (int j = 0; j < 64; ++j) h1[j] = 0.f;
    for (int k = 0; k < 32; ++k) {
        const float hk = hS[k * 256 + t];
        const float4* __restrict__ wr = reinterpret_cast<const float4*>(&sW1[k * 64]);
#pragma unroll
        for (int q = 0; q < 16; ++q) {
            const float4 wv = wr[q];
            h1[4 * q + 0] = fmaf(hk, wv.x, h1[4 * q + 0]);
            h1[4 * q + 1] = fmaf(hk, wv.y, h1[4 * q + 1]);
            h1[4 * q + 2] = fmaf(hk, wv.z, h1[4 * q + 2]);
            h1[4 * q + 3] = fmaf(hk, wv.w, h1[4 * q + 3]);
        }
    }
#pragma unroll
    for (int j = 0; j < 64; ++j) h1[j] = fmaxf(h1[j], 0.f);

    // ================= layer 2: h1[64] @ W2[64,64], relu ================
    float h2[64];
#pragma unroll
    for (int j = 0; j < 64; ++j) h2[j] = 0.f;

    // first 32 k's
#pragma unroll
    for (int k = 0; k < 32; ++k) hS[k * 256 + t] = h1[k];
    for (int k = 0; k < 32; ++k) {
        const float hk = hS[k * 256 + t];
        const float4* __restrict__ wr = reinterpret_cast<const float4*>(&sW2[k * 64]);
#pragma unroll
        for (int q = 0; q < 16; ++q) {
            const float4 wv = wr[q];
            h2[4 * q + 0] = fmaf(hk, wv.x, h2[4 * q + 0]);
            h2[4 * q + 1] = fmaf(hk, wv.y, h2[4 * q + 1]);
            h2[4 * q + 2] = fmaf(hk, wv.z, h2[4 * q + 2]);
            h2[4 * q + 3] = fmaf(hk, wv.w, h2[4 * q + 3]);
        }
    }
    // second 32 k's (overwrite own column; no cross-thread sharing -> no barrier)
#pragma unroll
    for (int k = 0; k < 32; ++k) hS[k * 256 + t] = h1[32 + k];
    for (int k = 0; k < 32; ++k) {
        const float hk = hS[k * 256 + t];
        const float4* __restrict__ wr = reinterpret_cast<const float4*>(&sW2[(k + 32) * 64]);
#pragma unroll
        for (int q = 0; q < 16; ++q) {
            const float4 wv = wr[q];
            h2[4 * q + 0] = fmaf(hk, wv.x, h2[4 * q + 0]);
            h2[4 * q + 1] = fmaf(hk, wv.y, h2[4 * q + 1]);
            h2[4 * q + 2] = fmaf(hk, wv.z, h2[4 * q + 2]);
            h2[4 * q + 3] = fmaf(hk, wv.w, h2[4 * q + 3]);
        }
    }
#pragma unroll
    for (int j = 0; j < 64; ++j) h2[j] = fmaxf(h2[j], 0.f);

    // ================= layer 3: h2[64] @ W3[64,16] ======================
    float h3[16];
#pragma unroll
    for (int j = 0; j < 16; ++j) h3[j] = 0.f;

#pragma unroll
    for (int k = 0; k < 32; ++k) hS[k * 256 + t] = h2[k];
    for (int k = 0; k < 32; ++k) {
        const float hk = hS[k * 256 + t];
        const float4* __restrict__ wr = reinterpret_cast<const float4*>(&sW3[k * 16]);
#pragma unroll
        for (int q = 0; q < 4; ++q) {
            const float4 wv = wr[q];
            h3[4 * q + 0] = fmaf(hk, wv.x, h3[4 * q + 0]);
            h3[4 * q + 1] = fmaf(hk, wv.y, h3[4 * q + 1]);
            h3[4 * q + 2] = fmaf(hk, wv.z, h3[4 * q + 2]);
            h3[4 * q + 3] = fmaf(hk, wv.w, h3[4 * q + 3]);
        }
    }
#pragma unroll
    for (int k = 0; k < 32; ++k) hS[k * 256 + t] = h2[32 + k];
    for (int k = 0; k < 32; ++k) {
        const float hk = hS[k * 256 + t];
        const float4* __restrict__ wr = reinterpret_cast<const float4*>(&sW3[(k + 32) * 16]);
#pragma unroll
        for (int q = 0; q < 4; ++q) {
            const float4 wv = wr[q];
            h3[4 * q + 0] = fmaf(hk, wv.x, h3[4 * q + 0]);
            h3[4 * q + 1] = fmaf(hk, wv.y, h3[4 * q + 1]);
            h3[4 * q + 2] = fmaf(hk, wv.z, h3[4 * q + 2]);
            h3[4 * q + 3] = fmaf(hk, wv.w, h3[4 * q + 3]);
        }
    }

    // ---- write out [N,16]: 64B contiguous per thread, fully coalesced ----
    float4* __restrict__ o = reinterpret_cast<float4*>(out + (size_t)i * 16);
    o[0] = make_float4(h3[0],  h3[1],  h3[2],  h3[3]);
    o[1] = make_float4(h3[4],  h3[5],  h3[6],  h3[7]);
    o[2] = make_float4(h3[8],  h3[9],  h3[10], h3[11]);
    o[3] = make_float4(h3[12], h3[13], h3[14], h3[15]);
}

extern "C" void kernel_launch(void* const* d_in, const int* in_sizes, int n_in,
                              void* d_out, int out_size, void* d_ws, size_t ws_size,
                              hipStream_t stream) {
    const float* x     = (const float*)d_in[0];
    const float* table = (const float*)d_in[1];
    const float* W1    = (const float*)d_in[2];
    const float* W2    = (const float*)d_in[3];
    const float* W3    = (const float*)d_in[4];
    float* out = (float*)d_out;

    const int n = in_sizes[0] / 3;
    const int blocks = (n + 255) / 256;
    ngp_fused_kernel<<<blocks, 256, 0, stream>>>(x, table, W1, W2, W3, out, n);
}